// Round 20
// baseline (535.079 us; speedup 1.0000x reference)
//
#include <hip/hip_runtime.h>
#include <hip/hip_bf16.h>

#define GG 2048
#define PP 10
#define HHC 128
#define NSTEP 25
#define NROW (GG*PP)      // 20480
#define ASTR 216          // lstm Ahi stride (bf16)
#define LROWS 80          // real rows per lstm block
#define LB 768            // lstm threads per block (12 waves)
#define GPB 4             // graphs per graphconv block
#define ADJS 40           // adjacency row stride (u16)
#define HS 72             // hrow/hT stride (u16)

typedef __attribute__((ext_vector_type(8))) short bf16x8;
typedef __attribute__((ext_vector_type(16))) float f32x16;
typedef unsigned short ushort_t;

__device__ __forceinline__ float sigf(float x){ return 1.f/(1.f+__expf(-x)); }
__device__ __forceinline__ float tanhf_(float x){ return 2.f/(1.f+__expf(-2.f*x)) - 1.f; }

__device__ __forceinline__ ushort_t f2b(float f){
  union{float f; unsigned u;} v; v.f=f;
  unsigned r = v.u + 0x7FFFu + ((v.u>>16)&1u);
  return (ushort_t)(r>>16);
}
__device__ __forceinline__ float b2f(ushort_t u){
  union{unsigned u; float f;} v; v.u = ((unsigned)u)<<16; return v.f;
}

#define MFMA32(A,B,C) __builtin_amdgcn_mfma_f32_32x32x16_bf16(A,B,C,0,0,0)
#define BC8(u) __builtin_bit_cast(bf16x8, u)

__device__ __forceinline__ unsigned pk2(float a, float b){
  unsigned r;
  asm("v_cvt_pk_bf16_f32 %0, %1, %2" : "=v"(r) : "v"(a), "v"(b));
  return r;
}
__device__ __forceinline__ void swp(unsigned& x, unsigned& y){
  asm("v_permlane32_swap_b32 %0, %1" : "+v"(x), "+v"(y));
}
// Convert agg MFMA output d (scaled by s) into the two B-frags (ksteps 0,1)
// of the following feat MFMA (proven in R16).
__device__ __forceinline__ void mk_frags(const f32x16 d, float s,
                                         bf16x8& f0, bf16x8& f1){
  unsigned a0 = pk2(d[0]*s,  d[1]*s);
  unsigned a1 = pk2(d[2]*s,  d[3]*s);
  unsigned b0 = pk2(d[4]*s,  d[5]*s);
  unsigned b1 = pk2(d[6]*s,  d[7]*s);
  swp(a0,b0); swp(a1,b1);
  uint4 u0 = {a0, a1, b0, b1};
  f0 = BC8(u0);
  unsigned c0 = pk2(d[8]*s,  d[9]*s);
  unsigned c1 = pk2(d[10]*s, d[11]*s);
  unsigned e0 = pk2(d[12]*s, d[13]*s);
  unsigned e1 = pk2(d[14]*s, d[15]*s);
  swp(c0,e0); swp(c1,e1);
  uint4 u1 = {c0, c1, e0, e1};
  f1 = BC8(u1);
}

// ---------------------------------------------------------------------------
// LSTM weight pack (hi plane only).
// ---------------------------------------------------------------------------
__global__ __launch_bounds__(256) void prep_pack(
    const float* __restrict__ wih, const float* __restrict__ whh,
    const float* __restrict__ bih, const float* __restrict__ bhh,
    ushort_t* __restrict__ bph)
{
  int id = blockIdx.x*256 + threadIdx.x;   // 25*13*16*64 = 332800
  int lane = id & 63;
  int r  = id >> 6;
  int nt = r & 15;
  int r2 = r >> 4;
  int kstep = r2 % 13;
  int s     = r2 / 13;
  int col = nt*32 + (lane&31);
  int k0  = kstep*16 + ((lane>>5)<<3);
  ushort_t hi[8];
  #pragma unroll
  for (int j=0;j<8;j++){
    int k = k0+j;
    float w = 0.f;
    if (k < 64)       w = wih[((size_t)s*512+col)*66 + k];
    else if (k < 192) w = whh[((size_t)s*512+col)*128 + (k-64)];
    else if (k < 194) w = wih[((size_t)s*512+col)*66 + 64 + (k-192)];
    else if (k == 194) w = bih[(size_t)s*512+col] + bhh[(size_t)s*512+col];
    hi[j] = f2b(w);
  }
  uint4 uh;
  uh.x = hi[0] | ((unsigned)hi[1]<<16); uh.y = hi[2] | ((unsigned)hi[3]<<16);
  uh.z = hi[4] | ((unsigned)hi[5]<<16); uh.w = hi[6] | ((unsigned)hi[7]<<16);
  *(uint4*)&bph[(size_t)id*8] = uh;
}

// ---------------------------------------------------------------------------
// Graphconv weight pack (unchanged).
// ---------------------------------------------------------------------------
__global__ __launch_bounds__(256) void prep_gw(
    const float* __restrict__ wpb, const float* __restrict__ wnb,
    const float* __restrict__ wpd, const float* __restrict__ wnd,
    ushort_t* __restrict__ gw)
{
  int id = blockIdx.x*256 + threadIdx.x;   // 8192
  int lane = id & 63;
  int r = id >> 6;                          // 0..127
  int hl = r & 1, path = (r>>1)&1, slot = r>>2;
  int col = lane & 31;
  int kb = (lane>>5)*8;
  ushort_t outv[8];
  #pragma unroll
  for (int j=0;j<8;j++){
    float wv;
    if (slot < 4){
      int k = slot*16 + kb + j;
      wv = (path? wnb : wpb)[k*32 + col];
    } else {
      int sl = slot-4; int layer = sl/14, kstep = sl%14;
      int k = kstep*16 + kb + j;
      wv = (path? wnd : wpd)[((size_t)layer*224 + k)*32 + col];
    }
    ushort_t h = f2b(wv);
    outv[j] = hl ? f2b(wv - b2f(h)) : h;
  }
  uint4 u;
  u.x = outv[0]|((unsigned)outv[1]<<16); u.y = outv[2]|((unsigned)outv[3]<<16);
  u.z = outv[4]|((unsigned)outv[5]<<16); u.w = outv[6]|((unsigned)outv[7]<<16);
  *(uint4*)&gw[(size_t)id*8] = u;
}

// ---------------------------------------------------------------------------
// Graphconv v2.1 (unchanged from R19).
// ---------------------------------------------------------------------------
__global__ __launch_bounds__(256) void graphconv(
    const float* __restrict__ h0,
    const float* __restrict__ bpb, const float* __restrict__ bnb,
    const float* __restrict__ bpd, const float* __restrict__ bnd,
    const ushort_t* __restrict__ gw,
    const int* __restrict__ pos_adj, const int* __restrict__ neg_adj,
    ushort_t* __restrict__ xout)
{
  __shared__ __align__(16) ushort_t adjA[4][2][32*ADJS];  // 20.5 KB
  __shared__ __align__(16) ushort_t hT[64*HS];            // 9.2 KB [feat][row64]
  __shared__ __align__(16) ushort_t hrow[64*HS];          // 9.2 KB [row64][feat]
  __shared__ float dinv[4][64];                           // 1 KB

  const int t = threadIdx.x;
  const int lane = t & 63;
  const int w = t >> 6;
  const int pair = w >> 1;
  const int path = w & 1;
  const long g0 = (long)blockIdx.x * GPB;
  const int nrow = lane & 31;
  const int row64 = pair*32 + nrow;
  const int kof = (lane>>5)*8;
  const int fbase = 4*(lane>>5);
  const uint4* gw4 = (const uint4*)gw;

  {
    const uint4 z = {0u,0u,0u,0u};
    for (int i=t; i<2560; i+=256) ((uint4*)adjA)[i] = z;
    for (int i=t; i<576;  i+=256) ((uint4*)hT)[i]   = z;
  }
  __syncthreads();

  for (int idx=t; idx<400; idx+=256){
    int g=idx/100, e=idx%100, r=e/10, c=e%10;
    if (r!=c){
      ushort_t pv = pos_adj[(g0+g)*100+e] ? (ushort_t)0x3F80 : (ushort_t)0;
      ushort_t nv = neg_adj[(g0+g)*100+e] ? (ushort_t)0x3F80 : (ushort_t)0;
      int pr=g>>1, gi=g&1;
      int rr=gi*16+r, cc=gi*16+c;
      adjA[0][pr][rr*ADJS+cc]=pv;
      adjA[1][pr][rr*ADJS+cc]=nv;
      adjA[2][pr][cc*ADJS+rr]=pv;
      adjA[3][pr][cc*ADJS+rr]=nv;
    }
  }
  if (t < 160){
    int r40=t>>2, seg=t&3;
    int g=r40/10, p=r40%10;
    int r64 = g*16 + p;
    const float* hr = h0 + ((size_t)(g0+g)*10 + p)*32 + seg*8;
    float4 v0=((const float4*)hr)[0], v1=((const float4*)hr)[1];
    float vv[8]={v0.x,v0.y,v0.z,v0.w,v1.x,v1.y,v1.z,v1.w};
    #pragma unroll
    for (int j=0;j<8;j++){
      ushort_t hi_=f2b(vv[j]);
      hrow[r64*HS + seg*8+j]      = hi_;
      hrow[r64*HS + 32 + seg*8+j] = f2b(vv[j]-b2f(hi_));
      hT[(seg*8+j)*HS + r64]      = hi_;
    }
  }
  if (t < 64){
    int g=t>>4, p=t&15;
    float rp=0,rn=0,cp=0,cn=0;
    if (p<10){
      const int* pb = pos_adj + (g0+g)*100;
      const int* nb = neg_adj + (g0+g)*100;
      for (int c=0;c<10;c++) if (c!=p){
        rp+=(float)pb[p*10+c]; rn+=(float)nb[p*10+c];
        cp+=(float)pb[c*10+p]; cn+=(float)nb[c*10+p];
      }
      rp=1.f/fmaxf(rp,1.f); rn=1.f/fmaxf(rn,1.f);
      cp=1.f/fmaxf(cp,1.f); cn=1.f/fmaxf(cn,1.f);
    }
    dinv[0][t]=rp; dinv[1][t]=rn; dinv[2][t]=cp; dinv[3][t]=cn;
  }
  __syncthreads();

  {
    f32x16 d;
    #pragma unroll
    for (int i=0;i<16;i++) d[i]=0.f;
    #pragma unroll
    for (int ks=0;ks<2;++ks){
      bf16x8 a = *(const bf16x8*)&hT[nrow*HS + pair*32 + ks*16 + kof];
      bf16x8 b = *(const bf16x8*)&adjA[path][pair][nrow*ADJS + ks*16 + kof];
      d = MFMA32(a, b, d);
    }
    bf16x8 f0, f1;
    mk_frags(d, dinv[path][row64], f0, f1);

    f32x16 acc;
    #pragma unroll
    for (int i=0;i<16;i++) acc[i]=0.f;
    {
      uint4 wh = gw4[((0*2+path)*2+0)*64 + lane];
      uint4 wl = gw4[((0*2+path)*2+1)*64 + lane];
      acc = MFMA32(BC8(wh), f0, acc);
      acc = MFMA32(BC8(wl), f0, acc);
      wh = gw4[((1*2+path)*2+0)*64 + lane];
      wl = gw4[((1*2+path)*2+1)*64 + lane];
      acc = MFMA32(BC8(wh), f1, acc);
      acc = MFMA32(BC8(wl), f1, acc);
    }
    #pragma unroll
    for (int ks=0;ks<2;++ks){
      uint4 wh = gw4[(((ks+2)*2+path)*2+0)*64 + lane];
      uint4 wl = gw4[(((ks+2)*2+path)*2+1)*64 + lane];
      bf16x8 b  = *(const bf16x8*)&hrow[row64*HS + ks*16 + kof];
      bf16x8 bl = *(const bf16x8*)&hrow[row64*HS + 32 + ks*16 + kof];
      acc = MFMA32(BC8(wh), b,  acc);
      acc = MFMA32(BC8(wl), b,  acc);
      acc = MFMA32(BC8(wh), bl, acc);
    }
    const float* bs = path ? bnb : bpb;
    float v[16]; float ss = 0.f;
    #pragma unroll
    for (int i=0;i<16;i++){
      int f = fbase + (i&3) + 8*(i>>2);
      v[i] = acc[i] + bs[f];
      ss += v[i]*v[i];
    }
    ss += __shfl_xor(ss,32);
    float sc = 1.f/fmaxf(sqrtf(ss),1e-12f);
    ushort_t qv[16];
    #pragma unroll
    for (int i=0;i<16;i++) qv[i] = f2b(v[i]*sc);
    __syncthreads();
    #pragma unroll
    for (int q=0;q<4;q++)
      *(ushort4*)&hrow[row64*HS + path*32 + fbase + 8*q] =
        make_ushort4(qv[4*q],qv[4*q+1],qv[4*q+2],qv[4*q+3]);
    #pragma unroll
    for (int i=0;i<16;i++){
      int f = fbase + (i&3) + 8*(i>>2);
      hT[(path*32+f)*HS + row64] = qv[i];
    }
  }
  __syncthreads();

  #pragma unroll 1
  for (int layer=0; layer<2; ++layer){
    f32x16 acc;
    #pragma unroll
    for (int i=0;i<16;i++) acc[i]=0.f;
    const int slot0 = 4 + layer*14;
    #pragma unroll 1
    for (int b=0; b<6; ++b){
      const int hsel   = ((38 >> b) & 1) * 32;
      const int adjsel = (b<4) ? (b&1) : (b-2);
      f32x16 d;
      #pragma unroll
      for (int i=0;i<16;i++) d[i]=0.f;
      #pragma unroll
      for (int ks=0;ks<2;++ks){
        bf16x8 a  = *(const bf16x8*)&hT[(hsel+nrow)*HS + pair*32 + ks*16 + kof];
        bf16x8 bb = *(const bf16x8*)&adjA[adjsel][pair][nrow*ADJS + ks*16 + kof];
        d = MFMA32(a, bb, d);
      }
      bf16x8 f0, f1;
      mk_frags(d, dinv[adjsel][row64], f0, f1);
      {
        uint4 wh = gw4[(((slot0+2*b  )*2+path)*2+0)*64 + lane];
        uint4 wl = gw4[(((slot0+2*b  )*2+path)*2+1)*64 + lane];
        acc = MFMA32(BC8(wh), f0, acc);
        acc = MFMA32(BC8(wl), f0, acc);
        wh = gw4[(((slot0+2*b+1)*2+path)*2+0)*64 + lane];
        wl = gw4[(((slot0+2*b+1)*2+path)*2+1)*64 + lane];
        acc = MFMA32(BC8(wh), f1, acc);
        acc = MFMA32(BC8(wl), f1, acc);
      }
    }
    #pragma unroll
    for (int ks=0;ks<2;++ks){
      uint4 wh = gw4[(((slot0+12+ks)*2+path)*2+0)*64 + lane];
      uint4 wl = gw4[(((slot0+12+ks)*2+path)*2+1)*64 + lane];
      bf16x8 b = *(const bf16x8*)&hrow[row64*HS + path*32 + ks*16 + kof];
      acc = MFMA32(BC8(wh), b, acc);
      acc = MFMA32(BC8(wl), b, acc);
    }
    const float* bs = (path ? bnd : bpd) + layer*32;
    float v[16]; float ss = 0.f;
    #pragma unroll
    for (int i=0;i<16;i++){
      int f = fbase + (i&3) + 8*(i>>2);
      v[i] = acc[i] + bs[f];
      ss += v[i]*v[i];
    }
    ss += __shfl_xor(ss,32);
    float sc = 1.f/fmaxf(sqrtf(ss),1e-12f);
    ushort_t qv[16];
    #pragma unroll
    for (int i=0;i<16;i++) qv[i] = f2b(v[i]*sc);

    if (layer==0){
      __syncthreads();
      #pragma unroll
      for (int q=0;q<4;q++)
        *(ushort4*)&hrow[row64*HS + path*32 + fbase + 8*q] =
          make_ushort4(qv[4*q],qv[4*q+1],qv[4*q+2],qv[4*q+3]);
      #pragma unroll
      for (int i=0;i<16;i++){
        int f = fbase + (i&3) + 8*(i>>2);
        hT[(path*32+f)*HS + row64] = qv[i];
      }
      __syncthreads();
    } else {
      int p_ = row64 & 15;
      if (p_ < 10){
        long gid = g0 + (row64>>4);
        size_t base = ((size_t)(gid%25)*NROW + (size_t)(gid/25)*10 + p_)*64 + path*32;
        #pragma unroll
        for (int q=0;q<4;q++)
          *(ushort4*)&xout[base + fbase + 8*q] =
            make_ushort4(qv[4*q],qv[4*q+1],qv[4*q+2],qv[4*q+3]);
      }
    }
  }
}

// ---------------------------------------------------------------------------
// Persistent MFMA LSTM v12: quad-buffered Bh with write-ahead-2; barriers
// only after odd ksteps (6+1/step vs v10's 12+1). Staging regs identical to
// v10 (pa/pb, 16 dwords). Window proof: pair {even k, odd k} reads buffers
// {k,k+1}, writes {k+2,k+3} (mod 4) — disjoint; every write(m)->read(m+2)
// has a barrier between (odd-k barriers + end-of-step). bb advances (13%4=1)
// per step; pa/pb swap handles 13-odd slot parity.
// ---------------------------------------------------------------------------
#define LSTM_K4(K, CUR0, CUR1) do{                                      \
  {  /* write CUR (data m+2) into Bh[(bb+K+2)&3] */                     \
    const long m2 = (long)s*13 + (K) + 2;                               \
    if (m2 < (long)NSTEP*13){                                           \
      uint4* db = (uint4*)&BhAll[(size_t)((bb+(K)+2)&3)*8192];          \
      db[t] = CUR0;                                                     \
      if (t<256) db[768+t] = CUR1;                                      \
    }                                                                   \
  }                                                                     \
  {  /* reload CUR with data m+4 (consumed 2 ksteps later) */           \
    const long m4 = (long)s*13 + (K) + 4;                               \
    if (m4 < (long)NSTEP*13){                                           \
      const uint4* p = bph4 + (size_t)m4*1024;                          \
      CUR0 = p[t];                                                      \
      if (t<256) CUR1 = p[768+t];                                       \
    }                                                                   \
  }                                                                     \
  {  /* compute kstep K from Bh[(bb+K)&3] */                            \
    const ushort_t* bbuf = &BhAll[(size_t)((bb+(K))&3)*8192];           \
    bf16x8 af = *(const bf16x8*)&Ahi[arow*ASTR + (K)*16 + kof];         \
    uint4 b0 = *(const uint4*)&bbuf[(ng   )*512 + lane*8];              \
    uint4 b1 = *(const uint4*)&bbuf[(ng+ 4)*512 + lane*8];              \
    uint4 b2 = *(const uint4*)&bbuf[(ng+ 8)*512 + lane*8];              \
    uint4 b3 = *(const uint4*)&bbuf[(ng+12)*512 + lane*8];              \
    __builtin_amdgcn_s_setprio(1);                                      \
    acc0 = MFMA32(af, BC8(b0), acc0);                                   \
    acc1 = MFMA32(af, BC8(b1), acc1);                                   \
    acc2 = MFMA32(af, BC8(b2), acc2);                                   \
    acc3 = MFMA32(af, BC8(b3), acc3);                                   \
    __builtin_amdgcn_s_setprio(0);                                      \
  }                                                                     \
  if ((K)&1) __syncthreads();                                           \
}while(0)

__global__ __launch_bounds__(LB,3) void lstm_persist(
    const ushort_t* __restrict__ xbuf, const ushort_t* __restrict__ bph,
    const float* __restrict__ hx0, const float* __restrict__ cx0,
    const float* __restrict__ ai, float* __restrict__ outp)
{
  __shared__ __align__(16) ushort_t Ahi[96*ASTR];     // 41.5 KB
  __shared__ __align__(16) ushort_t BhAll[4*8192];    // 64 KB (quad buffer)

  const int t = threadIdx.x;
  const int lane = t & 63;
  const int w = t >> 6;
  const int mt = w >> 2;
  const int ng = w & 3;
  const long rbase = (long)blockIdx.x * LROWS;
  const int c = ng*32 + (lane&31);
  const int kof = (lane>>5)*8;
  const int arow = mt*32 + (lane&31);
  const uint4* bph4 = (const uint4*)bph;

  for (int i=t; i<96*ASTR/2; i+=LB) ((unsigned*)Ahi)[i] = 0u;
  __syncthreads();
  if (t < LROWS){
    Ahi[t*ASTR+194] = 0x3F80;
    long R = rbase + t; int g=(int)(R/10), p=(int)(R%10);
    const float* aip = ai + (((size_t)g*5+0)*10+p)*2;
    Ahi[t*ASTR+192]=f2b(aip[0]); Ahi[t*ASTR+193]=f2b(aip[1]);
  }
  if (t < 640){
    int row=t>>3, c0=(t&7)*8;
    *(uint4*)&Ahi[row*ASTR+c0] = *(const uint4*)&xbuf[((size_t)rbase+row)*64 + c0];
  }
  float cxr[16];
  #pragma unroll
  for (int i=0;i<16;i++){
    int rof=(i&3)+8*(i>>2)+4*(lane>>5);
    int lr2=mt*32+rof;
    if (lr2 < LROWS){
      long R=rbase+lr2;
      Ahi[lr2*ASTR+64+c] = f2b(hx0[(size_t)R*HHC+c]);
      cxr[i]=cx0[(size_t)R*HHC+c];
    } else cxr[i]=0.f;
  }
  // prologue: Bh[0]<-k0, Bh[1]<-k1 ; pa<-k2, pb<-k3 (register stage)
  uint4 pa0, pa1, pb0, pb1;
  {
    uint4* d0 = (uint4*)&BhAll[0];
    d0[t] = bph4[t];
    if (t<256) d0[768+t] = bph4[768+t];
    uint4* d1 = (uint4*)&BhAll[8192];
    d1[t] = bph4[1024+t];
    if (t<256) d1[768+t] = bph4[1024+768+t];
    pa0 = bph4[2048+t];
    if (t<256) pa1 = bph4[2048+768+t];
    pb0 = bph4[3072+t];
    if (t<256) pb1 = bph4[3072+768+t];
  }
  __syncthreads();

  int bb = 0;
  #pragma unroll 1
  for (int s=0; s<NSTEP; ++s){
    f32x16 acc0, acc1, acc2, acc3;
    #pragma unroll
    for (int i=0;i<16;i++){ acc0[i]=0.f; acc1[i]=0.f; acc2[i]=0.f; acc3[i]=0.f; }

    // T14: issue next step's x load now, write to LDS after the k-loop
    uint4 xh;
    const bool xload = (s < NSTEP-1) && (t < 640);
    if (xload){
      int row=t>>3, c0=(t&7)*8;
      xh = *(const uint4*)&xbuf[((size_t)(s+1)*NROW + rbase + row)*64 + c0];
    }

    LSTM_K4( 0, pa0,pa1);
    LSTM_K4( 1, pb0,pb1);
    LSTM_K4( 2, pa0,pa1);
    LSTM_K4( 3, pb0,pb1);
    LSTM_K4( 4, pa0,pa1);
    LSTM_K4( 5, pb0,pb1);
    LSTM_K4( 6, pa0,pa1);
    LSTM_K4( 7, pb0,pb1);
    LSTM_K4( 8, pa0,pa1);
    LSTM_K4( 9, pb0,pb1);
    LSTM_K4(10, pa0,pa1);
    LSTM_K4(11, pb0,pb1);
    LSTM_K4(12, pa0,pa1);
    // 13 odd -> slot parity flips: swap pa <-> pb for next step
    { uint4 t0=pa0, t1=pa1; pa0=pb0; pa1=pb1; pb0=t0; pb1=t1; }

    // cell update — own-wave acc complete; hx writes (cols 64..191) are
    // disjoint from any lagging wave's k12 reads (cols 192..207); hx reads
    // (ksteps 4..11) all completed at the k11 barrier.
    #pragma unroll
    for (int i=0;i<16;i++){
      int rof=(i&3)+8*(i>>2)+4*(lane>>5);
      int lr2=mt*32+rof;
      float ig=sigf(acc0[i]), fg=sigf(acc1[i]);
      float gg=tanhf_(acc2[i]), og=sigf(acc3[i]);
      float cn = fg*cxr[i] + ig*gg;
      cxr[i]=cn;
      float h = og*tanhf_(cn);
      if (lr2 < LROWS){
        long R=rbase+lr2;
        if (s==NSTEP-1){
          outp[(size_t)R*HHC+c]=h;
        } else {
          Ahi[lr2*ASTR+64+c] = f2b(h);
        }
      }
    }
    if (s < NSTEP-1){
      const bool newai = (((s+1)%5)==0);
      if (newai) __syncthreads();   // lagging k12 reads ai cols — order only when restaged
      if (xload){
        int row=t>>3, c0=(t&7)*8;
        *(uint4*)&Ahi[row*ASTR + c0] = xh;
      }
      if (newai && t<LROWS){
        long R=rbase+t; int g=(int)(R/10), p=(int)(R%10);
        const float* aip = ai + (((size_t)g*5+(s+1)/5)*10+p)*2;
        Ahi[t*ASTR+192]=f2b(aip[0]);
        Ahi[t*ASTR+193]=f2b(aip[1]);
      }
      __syncthreads();   // x/ai/hx + k12's Bh write visible before next step
      bb = (bb + 1) & 3; // 13 % 4 == 1
    }
  }
}

// ---------------------------------------------------------------------------
extern "C" void kernel_launch(void* const* d_in, const int* in_sizes, int n_in,
                              void* d_out, int out_size, void* d_ws, size_t ws_size,
                              hipStream_t stream)
{
  const float* h0  = (const float*)d_in[0];
  const float* ai  = (const float*)d_in[1];
  const float* wpb = (const float*)d_in[2];
  const float* bpb = (const float*)d_in[3];
  const float* wnb = (const float*)d_in[4];
  const float* bnb = (const float*)d_in[5];
  const float* wpd = (const float*)d_in[6];
  const float* bpd = (const float*)d_in[7];
  const float* wnd = (const float*)d_in[8];
  const float* bnd = (const float*)d_in[9];
  const float* wih = (const float*)d_in[10];
  const float* whh = (const float*)d_in[11];
  const float* bih = (const float*)d_in[12];
  const float* bhh = (const float*)d_in[13];
  const float* hx0 = (const float*)d_in[14];
  const float* cx0 = (const float*)d_in[15];
  const int* padj  = (const int*)d_in[16];
  const int* nadj  = (const int*)d_in[17];
  float* out = (float*)d_out;

  ushort_t* xbuf16 = (ushort_t*)d_ws;                        // 25*20480*64 u16
  ushort_t* bph = xbuf16 + (size_t)NSTEP*NROW*64;            // 2,662,400 u16
  ushort_t* gw  = bph + (size_t)NSTEP*13*16*64*8;            // 65,536 u16

  prep_pack<<<1300,256,0,stream>>>(wih,whh,bih,bhh,bph);
  prep_gw<<<32,256,0,stream>>>(wpb,wnb,wpd,wnd,gw);
  graphconv<<<12800,256,0,stream>>>(h0,bpb,bnb,bpd,bnd,gw,padj,nadj,xbuf16);
  lstm_persist<<<256,LB,0,stream>>>(xbuf16,bph,hx0,cx0,ai,out);
}

// Round 21
// 534.158 us; speedup vs baseline: 1.0017x; 1.0017x over previous
//
#include <hip/hip_runtime.h>
#include <hip/hip_bf16.h>

#define GG 2048
#define PP 10
#define HHC 128
#define NSTEP 25
#define NROW (GG*PP)      // 20480
#define ASTR 216          // lstm Ahi stride (bf16)
#define LROWS 80          // real rows per lstm block
#define LB 768            // lstm threads per block (12 waves)
#define GPB 4             // graphs per graphconv block
#define ADJS 40           // adjacency row stride (u16)
#define HS 72             // hrow/hT stride (u16)

typedef __attribute__((ext_vector_type(8))) short bf16x8;
typedef __attribute__((ext_vector_type(16))) float f32x16;
typedef unsigned short ushort_t;

__device__ __forceinline__ float sigf(float x){ return 1.f/(1.f+__expf(-x)); }
__device__ __forceinline__ float tanhf_(float x){ return 2.f/(1.f+__expf(-2.f*x)) - 1.f; }

__device__ __forceinline__ ushort_t f2b(float f){
  union{float f; unsigned u;} v; v.f=f;
  unsigned r = v.u + 0x7FFFu + ((v.u>>16)&1u);
  return (ushort_t)(r>>16);
}
__device__ __forceinline__ float b2f(ushort_t u){
  union{unsigned u; float f;} v; v.u = ((unsigned)u)<<16; return v.f;
}

#define MFMA32(A,B,C) __builtin_amdgcn_mfma_f32_32x32x16_bf16(A,B,C,0,0,0)
#define BC8(u) __builtin_bit_cast(bf16x8, u)

__device__ __forceinline__ unsigned pk2(float a, float b){
  unsigned r;
  asm("v_cvt_pk_bf16_f32 %0, %1, %2" : "=v"(r) : "v"(a), "v"(b));
  return r;
}
__device__ __forceinline__ void swp(unsigned& x, unsigned& y){
  asm("v_permlane32_swap_b32 %0, %1" : "+v"(x), "+v"(y));
}
// Convert agg MFMA output d (scaled by s) into the two B-frags (ksteps 0,1)
// of the following feat MFMA (proven in R16).
__device__ __forceinline__ void mk_frags(const f32x16 d, float s,
                                         bf16x8& f0, bf16x8& f1){
  unsigned a0 = pk2(d[0]*s,  d[1]*s);
  unsigned a1 = pk2(d[2]*s,  d[3]*s);
  unsigned b0 = pk2(d[4]*s,  d[5]*s);
  unsigned b1 = pk2(d[6]*s,  d[7]*s);
  swp(a0,b0); swp(a1,b1);
  uint4 u0 = {a0, a1, b0, b1};
  f0 = BC8(u0);
  unsigned c0 = pk2(d[8]*s,  d[9]*s);
  unsigned c1 = pk2(d[10]*s, d[11]*s);
  unsigned e0 = pk2(d[12]*s, d[13]*s);
  unsigned e1 = pk2(d[14]*s, d[15]*s);
  swp(c0,e0); swp(c1,e1);
  uint4 u1 = {c0, c1, e0, e1};
  f1 = BC8(u1);
}

// ---------------------------------------------------------------------------
// LSTM weight pack (hi plane only).
// ---------------------------------------------------------------------------
__global__ __launch_bounds__(256) void prep_pack(
    const float* __restrict__ wih, const float* __restrict__ whh,
    const float* __restrict__ bih, const float* __restrict__ bhh,
    ushort_t* __restrict__ bph)
{
  int id = blockIdx.x*256 + threadIdx.x;   // 25*13*16*64 = 332800
  int lane = id & 63;
  int r  = id >> 6;
  int nt = r & 15;
  int r2 = r >> 4;
  int kstep = r2 % 13;
  int s     = r2 / 13;
  int col = nt*32 + (lane&31);
  int k0  = kstep*16 + ((lane>>5)<<3);
  ushort_t hi[8];
  #pragma unroll
  for (int j=0;j<8;j++){
    int k = k0+j;
    float w = 0.f;
    if (k < 64)       w = wih[((size_t)s*512+col)*66 + k];
    else if (k < 192) w = whh[((size_t)s*512+col)*128 + (k-64)];
    else if (k < 194) w = wih[((size_t)s*512+col)*66 + 64 + (k-192)];
    else if (k == 194) w = bih[(size_t)s*512+col] + bhh[(size_t)s*512+col];
    hi[j] = f2b(w);
  }
  uint4 uh;
  uh.x = hi[0] | ((unsigned)hi[1]<<16); uh.y = hi[2] | ((unsigned)hi[3]<<16);
  uh.z = hi[4] | ((unsigned)hi[5]<<16); uh.w = hi[6] | ((unsigned)hi[7]<<16);
  *(uint4*)&bph[(size_t)id*8] = uh;
}

// ---------------------------------------------------------------------------
// Graphconv weight pack (unchanged).
// ---------------------------------------------------------------------------
__global__ __launch_bounds__(256) void prep_gw(
    const float* __restrict__ wpb, const float* __restrict__ wnb,
    const float* __restrict__ wpd, const float* __restrict__ wnd,
    ushort_t* __restrict__ gw)
{
  int id = blockIdx.x*256 + threadIdx.x;   // 8192
  int lane = id & 63;
  int r = id >> 6;                          // 0..127
  int hl = r & 1, path = (r>>1)&1, slot = r>>2;
  int col = lane & 31;
  int kb = (lane>>5)*8;
  ushort_t outv[8];
  #pragma unroll
  for (int j=0;j<8;j++){
    float wv;
    if (slot < 4){
      int k = slot*16 + kb + j;
      wv = (path? wnb : wpb)[k*32 + col];
    } else {
      int sl = slot-4; int layer = sl/14, kstep = sl%14;
      int k = kstep*16 + kb + j;
      wv = (path? wnd : wpd)[((size_t)layer*224 + k)*32 + col];
    }
    ushort_t h = f2b(wv);
    outv[j] = hl ? f2b(wv - b2f(h)) : h;
  }
  uint4 u;
  u.x = outv[0]|((unsigned)outv[1]<<16); u.y = outv[2]|((unsigned)outv[3]<<16);
  u.z = outv[4]|((unsigned)outv[5]<<16); u.w = outv[6]|((unsigned)outv[7]<<16);
  *(uint4*)&gw[(size_t)id*8] = u;
}

// ---------------------------------------------------------------------------
// Graphconv v2.1: R16/R17 logic with vectorized (uint4) LDS zeroing.
// ---------------------------------------------------------------------------
__global__ __launch_bounds__(256) void graphconv(
    const float* __restrict__ h0,
    const float* __restrict__ bpb, const float* __restrict__ bnb,
    const float* __restrict__ bpd, const float* __restrict__ bnd,
    const ushort_t* __restrict__ gw,
    const int* __restrict__ pos_adj, const int* __restrict__ neg_adj,
    ushort_t* __restrict__ xout)
{
  __shared__ __align__(16) ushort_t adjA[4][2][32*ADJS];  // 20.5 KB
  __shared__ __align__(16) ushort_t hT[64*HS];            // 9.2 KB [feat][row64]
  __shared__ __align__(16) ushort_t hrow[64*HS];          // 9.2 KB [row64][feat]
  __shared__ float dinv[4][64];                           // 1 KB

  const int t = threadIdx.x;
  const int lane = t & 63;
  const int w = t >> 6;
  const int pair = w >> 1;
  const int path = w & 1;
  const long g0 = (long)blockIdx.x * GPB;
  const int nrow = lane & 31;
  const int row64 = pair*32 + nrow;
  const int kof = (lane>>5)*8;
  const int fbase = 4*(lane>>5);
  const uint4* gw4 = (const uint4*)gw;

  // ---- zero adjA + hT with b128 stores ----
  {
    const uint4 z = {0u,0u,0u,0u};
    for (int i=t; i<2560; i+=256) ((uint4*)adjA)[i] = z;
    for (int i=t; i<576;  i+=256) ((uint4*)hT)[i]   = z;
  }
  __syncthreads();

  // ---- fills: adjacency (2 layouts), h0 (hrow hi+lo, hT hi), degrees ----
  for (int idx=t; idx<400; idx+=256){
    int g=idx/100, e=idx%100, r=e/10, c=e%10;
    if (r!=c){
      ushort_t pv = pos_adj[(g0+g)*100+e] ? (ushort_t)0x3F80 : (ushort_t)0;
      ushort_t nv = neg_adj[(g0+g)*100+e] ? (ushort_t)0x3F80 : (ushort_t)0;
      int pr=g>>1, gi=g&1;
      int rr=gi*16+r, cc=gi*16+c;
      adjA[0][pr][rr*ADJS+cc]=pv;
      adjA[1][pr][rr*ADJS+cc]=nv;
      adjA[2][pr][cc*ADJS+rr]=pv;
      adjA[3][pr][cc*ADJS+rr]=nv;
    }
  }
  if (t < 160){
    int r40=t>>2, seg=t&3;
    int g=r40/10, p=r40%10;
    int r64 = g*16 + p;
    const float* hr = h0 + ((size_t)(g0+g)*10 + p)*32 + seg*8;
    float4 v0=((const float4*)hr)[0], v1=((const float4*)hr)[1];
    float vv[8]={v0.x,v0.y,v0.z,v0.w,v1.x,v1.y,v1.z,v1.w};
    #pragma unroll
    for (int j=0;j<8;j++){
      ushort_t hi_=f2b(vv[j]);
      hrow[r64*HS + seg*8+j]      = hi_;
      hrow[r64*HS + 32 + seg*8+j] = f2b(vv[j]-b2f(hi_));
      hT[(seg*8+j)*HS + r64]      = hi_;
    }
  }
  if (t < 64){
    int g=t>>4, p=t&15;
    float rp=0,rn=0,cp=0,cn=0;
    if (p<10){
      const int* pb = pos_adj + (g0+g)*100;
      const int* nb = neg_adj + (g0+g)*100;
      for (int c=0;c<10;c++) if (c!=p){
        rp+=(float)pb[p*10+c]; rn+=(float)nb[p*10+c];
        cp+=(float)pb[c*10+p]; cn+=(float)nb[c*10+p];
      }
      rp=1.f/fmaxf(rp,1.f); rn=1.f/fmaxf(rn,1.f);
      cp=1.f/fmaxf(cp,1.f); cn=1.f/fmaxf(cn,1.f);
    }
    dinv[0][t]=rp; dinv[1][t]=rn; dinv[2][t]=cp; dinv[3][t]=cn;
  }
  __syncthreads();

  {
    f32x16 d;
    #pragma unroll
    for (int i=0;i<16;i++) d[i]=0.f;
    #pragma unroll
    for (int ks=0;ks<2;++ks){
      bf16x8 a = *(const bf16x8*)&hT[nrow*HS + pair*32 + ks*16 + kof];
      bf16x8 b = *(const bf16x8*)&adjA[path][pair][nrow*ADJS + ks*16 + kof];
      d = MFMA32(a, b, d);
    }
    bf16x8 f0, f1;
    mk_frags(d, dinv[path][row64], f0, f1);

    f32x16 acc;
    #pragma unroll
    for (int i=0;i<16;i++) acc[i]=0.f;
    {
      uint4 wh = gw4[((0*2+path)*2+0)*64 + lane];
      uint4 wl = gw4[((0*2+path)*2+1)*64 + lane];
      acc = MFMA32(BC8(wh), f0, acc);
      acc = MFMA32(BC8(wl), f0, acc);
      wh = gw4[((1*2+path)*2+0)*64 + lane];
      wl = gw4[((1*2+path)*2+1)*64 + lane];
      acc = MFMA32(BC8(wh), f1, acc);
      acc = MFMA32(BC8(wl), f1, acc);
    }
    #pragma unroll
    for (int ks=0;ks<2;++ks){
      uint4 wh = gw4[(((ks+2)*2+path)*2+0)*64 + lane];
      uint4 wl = gw4[(((ks+2)*2+path)*2+1)*64 + lane];
      bf16x8 b  = *(const bf16x8*)&hrow[row64*HS + ks*16 + kof];
      bf16x8 bl = *(const bf16x8*)&hrow[row64*HS + 32 + ks*16 + kof];
      acc = MFMA32(BC8(wh), b,  acc);
      acc = MFMA32(BC8(wl), b,  acc);
      acc = MFMA32(BC8(wh), bl, acc);
    }
    const float* bs = path ? bnb : bpb;
    float v[16]; float ss = 0.f;
    #pragma unroll
    for (int i=0;i<16;i++){
      int f = fbase + (i&3) + 8*(i>>2);
      v[i] = acc[i] + bs[f];
      ss += v[i]*v[i];
    }
    ss += __shfl_xor(ss,32);
    float sc = 1.f/fmaxf(sqrtf(ss),1e-12f);
    ushort_t qv[16];
    #pragma unroll
    for (int i=0;i<16;i++) qv[i] = f2b(v[i]*sc);
    __syncthreads();   // all reads of hrow/hT done
    #pragma unroll
    for (int q=0;q<4;q++)
      *(ushort4*)&hrow[row64*HS + path*32 + fbase + 8*q] =
        make_ushort4(qv[4*q],qv[4*q+1],qv[4*q+2],qv[4*q+3]);
    #pragma unroll
    for (int i=0;i<16;i++){
      int f = fbase + (i&3) + 8*(i>>2);
      hT[(path*32+f)*HS + row64] = qv[i];
    }
  }
  __syncthreads();

  #pragma unroll 1
  for (int layer=0; layer<2; ++layer){
    f32x16 acc;
    #pragma unroll
    for (int i=0;i<16;i++) acc[i]=0.f;
    const int slot0 = 4 + layer*14;
    #pragma unroll 1
    for (int b=0; b<6; ++b){
      const int hsel   = ((38 >> b) & 1) * 32;
      const int adjsel = (b<4) ? (b&1) : (b-2);
      f32x16 d;
      #pragma unroll
      for (int i=0;i<16;i++) d[i]=0.f;
      #pragma unroll
      for (int ks=0;ks<2;++ks){
        bf16x8 a  = *(const bf16x8*)&hT[(hsel+nrow)*HS + pair*32 + ks*16 + kof];
        bf16x8 bb = *(const bf16x8*)&adjA[adjsel][pair][nrow*ADJS + ks*16 + kof];
        d = MFMA32(a, bb, d);
      }
      bf16x8 f0, f1;
      mk_frags(d, dinv[adjsel][row64], f0, f1);
      {
        uint4 wh = gw4[(((slot0+2*b  )*2+path)*2+0)*64 + lane];
        uint4 wl = gw4[(((slot0+2*b  )*2+path)*2+1)*64 + lane];
        acc = MFMA32(BC8(wh), f0, acc);
        acc = MFMA32(BC8(wl), f0, acc);
        wh = gw4[(((slot0+2*b+1)*2+path)*2+0)*64 + lane];
        wl = gw4[(((slot0+2*b+1)*2+path)*2+1)*64 + lane];
        acc = MFMA32(BC8(wh), f1, acc);
        acc = MFMA32(BC8(wl), f1, acc);
      }
    }
    #pragma unroll
    for (int ks=0;ks<2;++ks){
      uint4 wh = gw4[(((slot0+12+ks)*2+path)*2+0)*64 + lane];
      uint4 wl = gw4[(((slot0+12+ks)*2+path)*2+1)*64 + lane];
      bf16x8 b = *(const bf16x8*)&hrow[row64*HS + path*32 + ks*16 + kof];
      acc = MFMA32(BC8(wh), b, acc);
      acc = MFMA32(BC8(wl), b, acc);
    }
    const float* bs = (path ? bnd : bpd) + layer*32;
    float v[16]; float ss = 0.f;
    #pragma unroll
    for (int i=0;i<16;i++){
      int f = fbase + (i&3) + 8*(i>>2);
      v[i] = acc[i] + bs[f];
      ss += v[i]*v[i];
    }
    ss += __shfl_xor(ss,32);
    float sc = 1.f/fmaxf(sqrtf(ss),1e-12f);
    ushort_t qv[16];
    #pragma unroll
    for (int i=0;i<16;i++) qv[i] = f2b(v[i]*sc);

    if (layer==0){
      __syncthreads();
      #pragma unroll
      for (int q=0;q<4;q++)
        *(ushort4*)&hrow[row64*HS + path*32 + fbase + 8*q] =
          make_ushort4(qv[4*q],qv[4*q+1],qv[4*q+2],qv[4*q+3]);
      #pragma unroll
      for (int i=0;i<16;i++){
        int f = fbase + (i&3) + 8*(i>>2);
        hT[(path*32+f)*HS + row64] = qv[i];
      }
      __syncthreads();
    } else {
      int p_ = row64 & 15;
      if (p_ < 10){
        long gid = g0 + (row64>>4);
        size_t base = ((size_t)(gid%25)*NROW + (size_t)(gid/25)*10 + p_)*64 + path*32;
        #pragma unroll
        for (int q=0;q<4;q++)
          *(ushort4*)&xout[base + fbase + 8*q] =
            make_ushort4(qv[4*q],qv[4*q+1],qv[4*q+2],qv[4*q+3]);
      }
    }
  }
}

// ---------------------------------------------------------------------------
// Persistent MFMA LSTM v10 (proven optimum: 342 us, absmax 1.95e-3, no spill).
// 2-kstep-deep register prefetch of B; 12 in-loop barriers + 1/step.
// ---------------------------------------------------------------------------
#define LSTM_KSTEP(K, CUR0, CUR1, NXT0, NXT1) do{                       \
  const long m2 = (long)s*13 + (K) + 2;                                 \
  if (m2 < (long)NSTEP*13){                                             \
    const uint4* p = bph4 + (size_t)m2*1024;                            \
    NXT0 = p[t];                                                        \
    if (t<256) NXT1 = p[768+t];                                         \
  }                                                                     \
  {                                                                     \
    bf16x8 af = *(const bf16x8*)&Ahi[arow*ASTR + (K)*16 + kof];         \
    uint4 b0 = *(const uint4*)&Bh[buf][(ng   )*512 + lane*8];           \
    uint4 b1 = *(const uint4*)&Bh[buf][(ng+ 4)*512 + lane*8];           \
    uint4 b2 = *(const uint4*)&Bh[buf][(ng+ 8)*512 + lane*8];           \
    uint4 b3 = *(const uint4*)&Bh[buf][(ng+12)*512 + lane*8];           \
    __builtin_amdgcn_s_setprio(1);                                      \
    acc0 = MFMA32(af, BC8(b0), acc0);                                   \
    acc1 = MFMA32(af, BC8(b1), acc1);                                   \
    acc2 = MFMA32(af, BC8(b2), acc2);                                   \
    acc3 = MFMA32(af, BC8(b3), acc3);                                   \
    __builtin_amdgcn_s_setprio(0);                                      \
  }                                                                     \
  if ((long)s*13 + (K) + 1 < (long)NSTEP*13){                           \
    uint4* db = (uint4*)&Bh[buf^1][0];                                  \
    db[t] = CUR0;                                                       \
    if (t<256) db[768+t] = CUR1;                                        \
  }                                                                     \
  if ((K) < 12) __syncthreads();                                        \
  buf ^= 1;                                                             \
}while(0)

__global__ __launch_bounds__(LB,3) void lstm_persist(
    const ushort_t* __restrict__ xbuf, const ushort_t* __restrict__ bph,
    const float* __restrict__ hx0, const float* __restrict__ cx0,
    const float* __restrict__ ai, float* __restrict__ outp)
{
  __shared__ __align__(16) ushort_t Ahi[96*ASTR];   // 41.5 KB
  __shared__ __align__(16) ushort_t Bh[2][8192];    // 32 KB

  const int t = threadIdx.x;
  const int lane = t & 63;
  const int w = t >> 6;
  const int mt = w >> 2;
  const int ng = w & 3;
  const long rbase = (long)blockIdx.x * LROWS;
  const int c = ng*32 + (lane&31);
  const int kof = (lane>>5)*8;
  const int arow = mt*32 + (lane&31);
  const uint4* bph4 = (const uint4*)bph;

  for (int i=t; i<96*ASTR/2; i+=LB) ((unsigned*)Ahi)[i] = 0u;
  __syncthreads();
  if (t < LROWS){
    Ahi[t*ASTR+194] = 0x3F80;
    long R = rbase + t; int g=(int)(R/10), p=(int)(R%10);
    const float* aip = ai + (((size_t)g*5+0)*10+p)*2;
    Ahi[t*ASTR+192]=f2b(aip[0]); Ahi[t*ASTR+193]=f2b(aip[1]);
  }
  if (t < 640){
    int row=t>>3, c0=(t&7)*8;
    *(uint4*)&Ahi[row*ASTR+c0] = *(const uint4*)&xbuf[((size_t)rbase+row)*64 + c0];
  }
  float cxr[16];
  #pragma unroll
  for (int i=0;i<16;i++){
    int rof=(i&3)+8*(i>>2)+4*(lane>>5);
    int lr2=mt*32+rof;
    if (lr2 < LROWS){
      long R=rbase+lr2;
      Ahi[lr2*ASTR+64+c] = f2b(hx0[(size_t)R*HHC+c]);
      cxr[i]=cx0[(size_t)R*HHC+c];
    } else cxr[i]=0.f;
  }
  // prologue: Bh[0] <- kstep 0; pa <- kstep 1
  uint4 pa0, pa1, pb0, pb1;
  {
    uint4* db = (uint4*)&Bh[0][0];
    db[t] = bph4[t];
    if (t<256) db[768+t] = bph4[768+t];
    pa0 = bph4[1024+t];
    if (t<256) pa1 = bph4[1024+768+t];
  }
  __syncthreads();

  int buf = 0;
  #pragma unroll 1
  for (int s=0; s<NSTEP; ++s){
    f32x16 acc0, acc1, acc2, acc3;
    #pragma unroll
    for (int i=0;i<16;i++){ acc0[i]=0.f; acc1[i]=0.f; acc2[i]=0.f; acc3[i]=0.f; }

    // T14: issue next step's x load now, write to LDS after the k-loop
    uint4 xh;
    const bool xload = (s < NSTEP-1) && (t < 640);
    if (xload){
      int row=t>>3, c0=(t&7)*8;
      xh = *(const uint4*)&xbuf[((size_t)(s+1)*NROW + rbase + row)*64 + c0];
    }

    LSTM_KSTEP( 0, pa0,pa1, pb0,pb1);
    LSTM_KSTEP( 1, pb0,pb1, pa0,pa1);
    LSTM_KSTEP( 2, pa0,pa1, pb0,pb1);
    LSTM_KSTEP( 3, pb0,pb1, pa0,pa1);
    LSTM_KSTEP( 4, pa0,pa1, pb0,pb1);
    LSTM_KSTEP( 5, pb0,pb1, pa0,pa1);
    LSTM_KSTEP( 6, pa0,pa1, pb0,pb1);
    LSTM_KSTEP( 7, pb0,pb1, pa0,pa1);
    LSTM_KSTEP( 8, pa0,pa1, pb0,pb1);
    LSTM_KSTEP( 9, pb0,pb1, pa0,pa1);
    LSTM_KSTEP(10, pa0,pa1, pb0,pb1);
    LSTM_KSTEP(11, pb0,pb1, pa0,pa1);
    LSTM_KSTEP(12, pa0,pa1, pb0,pb1);
    // parity fix: next step's "cur" (kstep s+1,1) was loaded into pb
    pa0 = pb0; pa1 = pb1;

    // cell update (Ahi hx-col writes safe: all hx ksteps (4..11) barriered)
    #pragma unroll
    for (int i=0;i<16;i++){
      int rof=(i&3)+8*(i>>2)+4*(lane>>5);
      int lr2=mt*32+rof;
      float ig=sigf(acc0[i]), fg=sigf(acc1[i]);
      float gg=tanhf_(acc2[i]), og=sigf(acc3[i]);
      float cn = fg*cxr[i] + ig*gg;
      cxr[i]=cn;
      float h = og*tanhf_(cn);
      if (lr2 < LROWS){
        long R=rbase+lr2;
        if (s==NSTEP-1){
          outp[(size_t)R*HHC+c]=h;
        } else {
          Ahi[lr2*ASTR+64+c] = f2b(h);
        }
      }
    }
    if (s < NSTEP-1){
      const bool newai = (((s+1)%5)==0);
      if (newai) __syncthreads();   // kstep12 reads ai cols — order only when restaged
      if (xload){
        int row=t>>3, c0=(t&7)*8;
        *(uint4*)&Ahi[row*ASTR + c0] = xh;
      }
      if (newai && t<LROWS){
        long R=rbase+t; int g=(int)(R/10), p=(int)(R%10);
        const float* aip = ai + (((size_t)g*5+(s+1)/5)*10+p)*2;
        Ahi[t*ASTR+192]=f2b(aip[0]);
        Ahi[t*ASTR+193]=f2b(aip[1]);
      }
      __syncthreads();   // staged x/ai + hx + Bh(s+1,0) visible for next step
    }
  }
}

// ---------------------------------------------------------------------------
extern "C" void kernel_launch(void* const* d_in, const int* in_sizes, int n_in,
                              void* d_out, int out_size, void* d_ws, size_t ws_size,
                              hipStream_t stream)
{
  const float* h0  = (const float*)d_in[0];
  const float* ai  = (const float*)d_in[1];
  const float* wpb = (const float*)d_in[2];
  const float* bpb = (const float*)d_in[3];
  const float* wnb = (const float*)d_in[4];
  const float* bnb = (const float*)d_in[5];
  const float* wpd = (const float*)d_in[6];
  const float* bpd = (const float*)d_in[7];
  const float* wnd = (const float*)d_in[8];
  const float* bnd = (const float*)d_in[9];
  const float* wih = (const float*)d_in[10];
  const float* whh = (const float*)d_in[11];
  const float* bih = (const float*)d_in[12];
  const float* bhh = (const float*)d_in[13];
  const float* hx0 = (const float*)d_in[14];
  const float* cx0 = (const float*)d_in[15];
  const int* padj  = (const int*)d_in[16];
  const int* nadj  = (const int*)d_in[17];
  float* out = (float*)d_out;

  ushort_t* xbuf16 = (ushort_t*)d_ws;                        // 25*20480*64 u16
  ushort_t* bph = xbuf16 + (size_t)NSTEP*NROW*64;            // 2,662,400 u16
  ushort_t* gw  = bph + (size_t)NSTEP*13*16*64*8;            // 65,536 u16

  prep_pack<<<1300,256,0,stream>>>(wih,whh,bih,bhh,bph);
  prep_gw<<<32,256,0,stream>>>(wpb,wnb,wpd,wnd,gw);
  graphconv<<<12800,256,0,stream>>>(h0,bpb,bnb,bpd,bnd,gw,padj,nadj,xbuf16);
  lstm_persist<<<256,LB,0,stream>>>(xbuf16,bph,hx0,cx0,ai,out);
}